// Round 1
// baseline (253.249 us; speedup 1.0000x reference)
//
#include <hip/hip_runtime.h>

#define BATCH 4
#define NATOMS 286
#define CIN 23
#define COUT 2
#define HDIM 100
#define NLAYERS 49
#define T_TAB 8192
#define RB 32            // table rows per workgroup
#define HP 128           // padded hidden dim (K and N for MFMA)
#define WST 136          // LDS/global row stride in elems (16B-aligned rows, breaks bank aliasing)
#define RCUT 4.5f

typedef __bf16 bf16x8 __attribute__((ext_vector_type(8)));
typedef float f32x4 __attribute__((ext_vector_type(4)));

// workspace layout (bytes)
#define OFF_WT   0
#define SZ_WT    (NLAYERS * HP * WST * 2)        // 1,705,984
#define OFF_WOUT (OFF_WT + SZ_WT)                // 1,705,984
#define SZ_WOUT  (48 * WST * 2)                  // 13,056
#define OFF_TAB  1719296                         // 256-aligned
#define SZ_TAB   (T_TAB * 48 * 4)                // 1,572,864
#define OFF_OBI  (OFF_TAB + SZ_TAB)              // 3,292,160

// ---------------------------------------------------------------------------
// Prep: transpose+pad+scale weights into bf16 [n][k] layout (B-operand order).
// Hidden: wT[l][n][k] = w_hidden[l][k][n] * 0.1        (1/sqrt(100) baked in)
// Out:    wOutT[n][k] = w_out[k][n] * 0.1 * Y00/2      (all epilogue scales baked)
// ---------------------------------------------------------------------------
__global__ __launch_bounds__(256) void se3_prep(const float* __restrict__ wh,
                                                const float* __restrict__ wo,
                                                __bf16* __restrict__ wT,
                                                __bf16* __restrict__ wOutT) {
    int idx = blockIdx.x * 256 + threadIdx.x;
    const int NWT = NLAYERS * HP * WST;          // 852,992
    if (idx < NWT) {
        int l = idx / (HP * WST);
        int rem = idx % (HP * WST);
        int n = rem / WST, k = rem % WST;
        float v = (n < HDIM && k < HDIM) ? wh[(l * HDIM + k) * HDIM + n] * 0.1f : 0.0f;
        wT[idx] = (__bf16)v;
    } else if (idx < NWT + 48 * WST) {
        int r2 = idx - NWT;
        int n = r2 / WST, k = r2 % WST;
        // 0.1 * Y00 / sqrt(n_norm) = 0.1 * 0.28209479177 / 2
        float v = (n < 46 && k < HDIM) ? wo[k * 46 + n] * 0.014104739588693802f : 0.0f;
        wOutT[r2] = (__bf16)v;
    }
}

// ---------------------------------------------------------------------------
// Stage A: build table R(r_t) for T_TAB samples of r in [0, 4.5].
// 256 WGs x 32 rows. 49 hidden layers of [32,128]@[128,128] bf16 MFMA.
// ---------------------------------------------------------------------------
__global__ __launch_bounds__(256) void se3_table(const float* __restrict__ w_in,
                                                 const __bf16* __restrict__ wT,
                                                 const __bf16* __restrict__ wOutT,
                                                 float* __restrict__ tab) {
    __shared__ __align__(16) __bf16 hA[2][RB * WST];     // 2 x 8.5 KB
    __shared__ __align__(16) __bf16 wBs[HP * WST];       // 34 KB
    const int tid = threadIdx.x;
    const int wg = blockIdx.x;

    // zero the padding columns k in [100,136) of both h buffers
    // (garbage bf16 bits could be NaN; NaN * 0 = NaN would poison MFMA)
    for (int p = tid; p < RB * (WST - HDIM); p += 256) {
        int r = p / (WST - HDIM);
        int k = HDIM + p % (WST - HDIM);
        hA[0][r * WST + k] = (__bf16)0.0f;
        hA[1][r * WST + k] = (__bf16)0.0f;
    }
    // first layer (K=3) in fp32 VALU: h1 = relu(basis(r) @ w_in / sqrt(3))
    for (int p = tid; p < RB * HDIM; p += 256) {
        int r = p / HDIM, j = p % HDIM;
        float rv = (float)(wg * RB + r) * (RCUT / (float)(T_TAB - 1));
        float acc = 0.0f;
#pragma unroll
        for (int k = 0; k < 3; ++k) {
            float x = (rv - 1.5f * (float)k) * (1.0f / 1.5f);
            float c = __cosf(1.5707963267948966f * x);
            float bas = (fabsf(x) < 1.0f) ? c * c : 0.0f;
            acc += bas * w_in[k * HDIM + j];
        }
        hA[0][r * WST + j] = (__bf16)fmaxf(acc * 0.5773502691896258f, 0.0f);
    }
    __syncthreads();

    const int wv = tid >> 6, lane = tid & 63;
    const int quad = lane >> 4, l16 = lane & 15;
    int cur = 0;

    for (int l = 0; l < NLAYERS; ++l) {
        // stage this layer's weights (bf16 [n][k], 34,816 B) into LDS
        const uint4* src = (const uint4*)(wT + l * HP * WST);
        uint4* dst = (uint4*)&wBs[0];
        for (int t = tid; t < HP * WST / 8; t += 256) dst[t] = src[t];
        __syncthreads();

        f32x4 accv[4];
#pragma unroll
        for (int tile = 0; tile < 4; ++tile) {
            int ct = wv * 2 + (tile & 1);   // col tile 0..7
            int rt = tile >> 1;             // row tile 0..1
            f32x4 a = {0.0f, 0.0f, 0.0f, 0.0f};
#pragma unroll
            for (int ks = 0; ks < 4; ++ks) {
                bf16x8 af = *(const bf16x8*)&hA[cur][(rt * 16 + l16) * WST + ks * 32 + quad * 8];
                bf16x8 bf = *(const bf16x8*)&wBs[(ct * 16 + l16) * WST + ks * 32 + quad * 8];
                a = __builtin_amdgcn_mfma_f32_16x16x32_bf16(af, bf, a, 0, 0, 0);
            }
            accv[tile] = a;
        }
        int nxt = cur ^ 1;
#pragma unroll
        for (int tile = 0; tile < 4; ++tile) {
            int ct = wv * 2 + (tile & 1);
            int rt = tile >> 1;
#pragma unroll
            for (int rg = 0; rg < 4; ++rg) {
                float v = fmaxf(accv[tile][rg], 0.0f);  // relu (0.1 scale baked in W)
                hA[nxt][(rt * 16 + quad * 4 + rg) * WST + ct * 16 + l16] = (__bf16)v;
            }
        }
        __syncthreads();
        cur = nxt;
    }

    // output layer: [32,128] @ [128,48] -> tab (fp32, all scales baked)
    {
        const uint4* src = (const uint4*)wOutT;
        uint4* dst = (uint4*)&wBs[0];
        for (int t = tid; t < 48 * WST / 8; t += 256) dst[t] = src[t];
        __syncthreads();
        if (wv < 3) {
            int ct = wv;
#pragma unroll
            for (int rt = 0; rt < 2; ++rt) {
                f32x4 a = {0.0f, 0.0f, 0.0f, 0.0f};
#pragma unroll
                for (int ks = 0; ks < 4; ++ks) {
                    bf16x8 af = *(const bf16x8*)&hA[cur][(rt * 16 + l16) * WST + ks * 32 + quad * 8];
                    bf16x8 bf = *(const bf16x8*)&wBs[(ct * 16 + l16) * WST + ks * 32 + quad * 8];
                    a = __builtin_amdgcn_mfma_f32_16x16x32_bf16(af, bf, a, 0, 0, 0);
                }
#pragma unroll
                for (int rg = 0; rg < 4; ++rg) {
                    int row = wg * RB + rt * 16 + quad * 4 + rg;
                    tab[row * 48 + ct * 16 + l16] = a[rg];
                }
            }
        }
    }
}

// ---------------------------------------------------------------------------
// Stage B: per-(b,i) convolution. out[b,i,o] = relu( sum_{j,c} R(r_ij)[o,c] f[b,j,c] )
// (scale already baked into the table). 4 waves split the j loop; lanes 0..45
// own the 46 (o,c) entries and lerp the table.
// ---------------------------------------------------------------------------
__global__ __launch_bounds__(256) void se3_conv(const float* __restrict__ feat,
                                                const float* __restrict__ geo,
                                                const float* __restrict__ tab,
                                                float* __restrict__ outBI) {
    __shared__ float fS[NATOMS * CIN];   // 26.3 KB
    __shared__ float gS[NATOMS * 3];     // 3.4 KB
    __shared__ float sacc[4][46];
    const int b = blockIdx.x / NATOMS;
    const int i = blockIdx.x % NATOMS;
    const int tid = threadIdx.x;

    for (int p = tid; p < NATOMS * CIN; p += 256) fS[p] = feat[b * NATOMS * CIN + p];
    for (int p = tid; p < NATOMS * 3; p += 256) gS[p] = geo[b * NATOMS * 3 + p];
    __syncthreads();

    const float xi = gS[i * 3 + 0], yi = gS[i * 3 + 1], zi = gS[i * 3 + 2];
    const int wv = tid >> 6, lane = tid & 63;
    const int o = lane / CIN;            // valid for lane < 46
    const int c = lane - o * CIN;
    const bool act = lane < 46;
    float acc = 0.0f;

#pragma unroll 2
    for (int j = wv; j < NATOMS; j += 4) {
        float dx = xi - gS[j * 3 + 0];
        float dy = yi - gS[j * 3 + 1];
        float dz = zi - gS[j * 3 + 2];
        float r = sqrtf(dx * dx + dy * dy + dz * dz + 1e-12f);
        float u = r * ((float)(T_TAB - 1) / RCUT);
        int i0 = min((int)u, T_TAB - 2);
        float fr = fminf(u - (float)i0, 1.0f);   // clamp => exact 0 beyond cutoff
        if (act) {
            float v0 = tab[i0 * 48 + lane];
            float v1 = tab[(i0 + 1) * 48 + lane];
            float v = v0 + fr * (v1 - v0);
            acc += v * fS[j * CIN + c];
        }
    }
    if (act) sacc[wv][lane] = acc;
    __syncthreads();
    if (tid < COUT) {
        float s = 0.0f;
        for (int w = 0; w < 4; ++w)
            for (int cc = 0; cc < CIN; ++cc) s += sacc[w][tid * CIN + cc];
        outBI[blockIdx.x * COUT + tid] = fmaxf(s, 0.0f);
    }
}

// ---------------------------------------------------------------------------
// Stage C: mean over atoms, linear head. out[b] = mean_i(out[b,i,:]) @ lin_w + lin_b
// ---------------------------------------------------------------------------
__global__ __launch_bounds__(256) void se3_final(const float* __restrict__ outBI,
                                                 const float* __restrict__ lw,
                                                 const float* __restrict__ lb,
                                                 float* __restrict__ out) {
    __shared__ float red[256];
    __shared__ float red2[8];
    const int tid = threadIdx.x;
    const int g = tid >> 5, s = tid & 31;    // g: (b,o) group 0..7
    const int b = g >> 1, o = g & 1;
    float p = 0.0f;
    for (int i = s; i < NATOMS; i += 32) p += outBI[(b * NATOMS + i) * COUT + o];
    red[tid] = p;
    __syncthreads();
    if (tid < 8) {
        float sum = 0.0f;
        for (int q = 0; q < 32; ++q) sum += red[tid * 32 + q];
        red2[tid] = sum;
    }
    __syncthreads();
    if (tid < BATCH) {
        float p0 = red2[tid * 2 + 0] * (1.0f / (float)NATOMS);
        float p1 = red2[tid * 2 + 1] * (1.0f / (float)NATOMS);
        out[tid] = p0 * lw[0] + p1 * lw[1] + lb[0];
    }
}

// ---------------------------------------------------------------------------
extern "C" void kernel_launch(void* const* d_in, const int* in_sizes, int n_in,
                              void* d_out, int out_size, void* d_ws, size_t ws_size,
                              hipStream_t stream) {
    const float* feat = (const float*)d_in[0];   // [4,286,23]
    const float* geo  = (const float*)d_in[1];   // [4,286,3]
    // d_in[2] = num_atoms (static 286, unused)
    const float* w_in = (const float*)d_in[3];   // [3,100]
    const float* w_h  = (const float*)d_in[4];   // [49,100,100]
    const float* w_o  = (const float*)d_in[5];   // [100,46]
    const float* lw   = (const float*)d_in[6];   // [2]
    const float* lb   = (const float*)d_in[7];   // [1]

    char* ws = (char*)d_ws;
    __bf16* wT    = (__bf16*)(ws + OFF_WT);
    __bf16* wOutT = (__bf16*)(ws + OFF_WOUT);
    float*  tab   = (float*)(ws + OFF_TAB);
    float*  outBI = (float*)(ws + OFF_OBI);

    const int prep_elems = NLAYERS * HP * WST + 48 * WST;
    se3_prep<<<(prep_elems + 255) / 256, 256, 0, stream>>>(w_h, w_o, wT, wOutT);
    se3_table<<<T_TAB / RB, 256, 0, stream>>>(w_in, wT, wOutT, tab);
    se3_conv<<<BATCH * NATOMS, 256, 0, stream>>>(feat, geo, tab, outBI);
    se3_final<<<1, 256, 0, stream>>>(outBI, lw, lb, (float*)d_out);
}

// Round 2
// 136.970 us; speedup vs baseline: 1.8489x; 1.8489x over previous
//
#include <hip/hip_runtime.h>

#define BATCH 4
#define NATOMS 286
#define CIN 23
#define COUT 2
#define HDIM 100
#define NLAYERS 49
#define T_TAB 4096
#define RB 16            // table rows per workgroup -> grid = 256 WGs
#define RCUT 4.5f

typedef __bf16 bf16x8 __attribute__((ext_vector_type(8)));
typedef float f32x4 __attribute__((ext_vector_type(4)));

// ---- workspace layout (bytes) ----
// wS:    [49][8 nt][4 ks][64 lane][8] bf16  — hidden weights, fragment order
// wOutS: [3 nt][4 ks][64 lane][8] bf16      — output layer, fragment order
// tab:   [4096][48] f32
// outBI: [1144][2] f32
#define OFF_WS    0
#define SZ_WS     (NLAYERS * 8 * 4 * 64 * 8 * 2)    // 1,605,632
#define OFF_WOUT  (OFF_WS + SZ_WS)
#define SZ_WOUT   (3 * 4 * 64 * 8 * 2)              // 12,288
#define OFF_TAB   (OFF_WOUT + SZ_WOUT)              // 1,617,920
#define SZ_TAB    (T_TAB * 48 * 4)                  // 786,432
#define OFF_OBI   (OFF_TAB + SZ_TAB)                // 2,404,352

// ---------------------------------------------------------------------------
// Prep: emit weights in per-lane MFMA B-fragment order (bf16), scales baked.
// Hidden frag element: wS[((l*8+nt)*4+ks)*64+lane][j] =
//     wh[l][k][n]*0.1 with n = nt*16+(lane&15), k = ks*32+(lane>>4)*8+j
// Out  frag: same mapping on wo[k][n] * 0.1 * Y00/sqrt(4), n<46.
// ---------------------------------------------------------------------------
__global__ __launch_bounds__(256) void se3_prep(const float* __restrict__ wh,
                                                const float* __restrict__ wo,
                                                __bf16* __restrict__ wS,
                                                __bf16* __restrict__ wOutS) {
    const int idx = blockIdx.x * 256 + threadIdx.x;
    const int NH = NLAYERS * 8 * 4 * 64;     // 100,352 hidden fragments-lanes
    if (idx < NH) {
        int lane = idx & 63;
        int ks = (idx >> 6) & 3;
        int nt = (idx >> 8) & 7;
        int l = idx >> 11;
        int n = nt * 16 + (lane & 15);
        int k0 = ks * 32 + ((lane >> 4) << 3);
        __bf16 v[8];
#pragma unroll
        for (int j = 0; j < 8; ++j) {
            int k = k0 + j;
            float x = (n < HDIM && k < HDIM) ? wh[(l * HDIM + k) * HDIM + n] * 0.1f : 0.0f;
            v[j] = (__bf16)x;
        }
        *(bf16x8*)&wS[idx * 8] = *(bf16x8*)v;
    } else if (idx < NH + 3 * 4 * 64) {
        int r = idx - NH;
        int lane = r & 63;
        int ks = (r >> 6) & 3;
        int nt = r >> 8;
        int n = nt * 16 + (lane & 15);
        int k0 = ks * 32 + ((lane >> 4) << 3);
        __bf16 v[8];
#pragma unroll
        for (int j = 0; j < 8; ++j) {
            int k = k0 + j;
            // 0.1 * Y00 / sqrt(n_norm) = 0.1 * 0.28209479177 / 2
            float x = (n < 46 && k < HDIM) ? wo[k * 46 + n] * 0.014104739588693802f : 0.0f;
            v[j] = (__bf16)x;
        }
        *(bf16x8*)&wOutS[r * 8] = *(bf16x8*)v;
    }
}

// ---------------------------------------------------------------------------
// Stage A: table of R(r) at T_TAB samples. 256 WGs x 16 rows.
// Weights direct-from-global (fragment layout) with 1-layer-ahead register
// prefetch; h ping-pong in LDS with XOR chunk swizzle; one barrier per layer.
// h element [r][k] stored at  r*128 + (((k>>3) ^ r) << 3) + (k&7).
// ---------------------------------------------------------------------------
__global__ __launch_bounds__(256) void se3_table(const float* __restrict__ w_in,
                                                 const __bf16* __restrict__ wS,
                                                 const __bf16* __restrict__ wOutS,
                                                 float* __restrict__ tab) {
    __shared__ __align__(16) __bf16 hA[2][RB * 128];   // 2 x 4 KB
    const int tid = threadIdx.x;
    const int wg = blockIdx.x;

    // layer 0 (K=3) in fp32 VALU; cols 100..127 zeroed
    for (int p = tid; p < RB * 128; p += 256) {
        int r = p >> 7, j = p & 127;
        float acc = 0.0f;
        if (j < HDIM) {
            float rv = (float)(wg * RB + r) * (RCUT / (float)(T_TAB - 1));
#pragma unroll
            for (int k = 0; k < 3; ++k) {
                float x = (rv - 1.5f * (float)k) * (1.0f / 1.5f);
                float c = __cosf(1.5707963267948966f * x);
                float bas = (fabsf(x) < 1.0f) ? c * c : 0.0f;
                acc += bas * w_in[k * HDIM + j];
            }
            acc = fmaxf(acc * 0.5773502691896258f, 0.0f);   // 1/sqrt(3), relu
        }
        hA[0][r * 128 + (((j >> 3) ^ r) << 3) + (j & 7)] = (__bf16)acc;
    }
    __syncthreads();

    const int wv = tid >> 6, lane = tid & 63;
    const int quad = lane >> 4, l16 = lane & 15;
    const bf16x8* wp = (const bf16x8*)wS;   // [((l*8+nt)*4+ks)*64+lane]

    bf16x8 cw[8], nw[8];
#pragma unroll
    for (int t = 0; t < 8; ++t) {
        int nt = wv * 2 + (t >> 2), ks = t & 3;
        cw[t] = wp[((0 * 8 + nt) * 4 + ks) * 64 + lane];
    }

    int cur = 0;
    for (int l = 0; l < NLAYERS; ++l) {
        if (l + 1 < NLAYERS) {
#pragma unroll
            for (int t = 0; t < 8; ++t) {
                int nt = wv * 2 + (t >> 2), ks = t & 3;
                nw[t] = wp[(((l + 1) * 8 + nt) * 4 + ks) * 64 + lane];
            }
        }
        // A fragments: lane m=l16, k = ks*32 + quad*8 .. +8  (one chunk)
        bf16x8 af[4];
#pragma unroll
        for (int ks = 0; ks < 4; ++ks) {
            int kc = ks * 4 + quad;
            af[ks] = *(const bf16x8*)&hA[cur][l16 * 128 + ((kc ^ l16) << 3)];
        }
        f32x4 acc0 = {0.f, 0.f, 0.f, 0.f}, acc1 = {0.f, 0.f, 0.f, 0.f};
#pragma unroll
        for (int ks = 0; ks < 4; ++ks) {
            acc0 = __builtin_amdgcn_mfma_f32_16x16x32_bf16(af[ks], cw[ks], acc0, 0, 0, 0);
            acc1 = __builtin_amdgcn_mfma_f32_16x16x32_bf16(af[ks], cw[4 + ks], acc1, 0, 0, 0);
        }
        int nxt = cur ^ 1;
#pragma unroll
        for (int rg = 0; rg < 4; ++rg) {
            int r = quad * 4 + rg;
            int n0 = (wv * 2) * 16 + l16;
            int n1 = (wv * 2 + 1) * 16 + l16;
            hA[nxt][r * 128 + (((n0 >> 3) ^ r) << 3) + (n0 & 7)] = (__bf16)fmaxf(acc0[rg], 0.0f);
            hA[nxt][r * 128 + (((n1 >> 3) ^ r) << 3) + (n1 & 7)] = (__bf16)fmaxf(acc1[rg], 0.0f);
        }
        __syncthreads();
        cur = nxt;
#pragma unroll
        for (int t = 0; t < 8; ++t) cw[t] = nw[t];
    }

    // output layer: [16,128] @ [128,48] -> tab rows (fp32, all scales baked)
    if (wv < 3) {
        bf16x8 ow[4];
#pragma unroll
        for (int ks = 0; ks < 4; ++ks)
            ow[ks] = ((const bf16x8*)wOutS)[(wv * 4 + ks) * 64 + lane];
        bf16x8 af[4];
#pragma unroll
        for (int ks = 0; ks < 4; ++ks) {
            int kc = ks * 4 + quad;
            af[ks] = *(const bf16x8*)&hA[cur][l16 * 128 + ((kc ^ l16) << 3)];
        }
        f32x4 a = {0.f, 0.f, 0.f, 0.f};
#pragma unroll
        for (int ks = 0; ks < 4; ++ks)
            a = __builtin_amdgcn_mfma_f32_16x16x32_bf16(af[ks], ow[ks], a, 0, 0, 0);
#pragma unroll
        for (int rg = 0; rg < 4; ++rg) {
            int row = wg * RB + quad * 4 + rg;
            tab[row * 48 + wv * 16 + l16] = a[rg];
        }
    }
}

// ---------------------------------------------------------------------------
// Stage B: per-(b,i) convolution. out[b,i,o] = relu( sum_{j,c} R(r_ij)[o,c] f[b,j,c] )
// ---------------------------------------------------------------------------
__global__ __launch_bounds__(256) void se3_conv(const float* __restrict__ feat,
                                                const float* __restrict__ geo,
                                                const float* __restrict__ tab,
                                                float* __restrict__ outBI) {
    __shared__ float fS[NATOMS * CIN];   // 26.3 KB
    __shared__ float gS[NATOMS * 3];     // 3.4 KB
    __shared__ float sacc[4][46];
    const int b = blockIdx.x / NATOMS;
    const int i = blockIdx.x % NATOMS;
    const int tid = threadIdx.x;

    for (int p = tid; p < NATOMS * CIN; p += 256) fS[p] = feat[b * NATOMS * CIN + p];
    for (int p = tid; p < NATOMS * 3; p += 256) gS[p] = geo[b * NATOMS * 3 + p];
    __syncthreads();

    const float xi = gS[i * 3 + 0], yi = gS[i * 3 + 1], zi = gS[i * 3 + 2];
    const int wv = tid >> 6, lane = tid & 63;
    const int o = lane / CIN;            // valid for lane < 46
    const int c = lane - o * CIN;
    const bool act = lane < 46;
    float acc = 0.0f;

#pragma unroll 2
    for (int j = wv; j < NATOMS; j += 4) {
        float dx = xi - gS[j * 3 + 0];
        float dy = yi - gS[j * 3 + 1];
        float dz = zi - gS[j * 3 + 2];
        float r = sqrtf(dx * dx + dy * dy + dz * dz + 1e-12f);
        float u = r * ((float)(T_TAB - 1) / RCUT);
        int i0 = min((int)u, T_TAB - 2);
        float fr = fminf(u - (float)i0, 1.0f);   // clamp => exact 0 beyond cutoff
        if (act) {
            float v0 = tab[i0 * 48 + lane];
            float v1 = tab[(i0 + 1) * 48 + lane];
            float v = v0 + fr * (v1 - v0);
            acc += v * fS[j * CIN + c];
        }
    }
    if (act) sacc[wv][lane] = acc;
    __syncthreads();
    if (tid < COUT) {
        float s = 0.0f;
        for (int w = 0; w < 4; ++w)
            for (int cc = 0; cc < CIN; ++cc) s += sacc[w][tid * CIN + cc];
        outBI[blockIdx.x * COUT + tid] = fmaxf(s, 0.0f);
    }
}

// ---------------------------------------------------------------------------
// Stage C: mean over atoms, linear head.
// ---------------------------------------------------------------------------
__global__ __launch_bounds__(256) void se3_final(const float* __restrict__ outBI,
                                                 const float* __restrict__ lw,
                                                 const float* __restrict__ lb,
                                                 float* __restrict__ out) {
    __shared__ float red[256];
    __shared__ float red2[8];
    const int tid = threadIdx.x;
    const int g = tid >> 5, s = tid & 31;    // g: (b,o) group 0..7
    const int b = g >> 1, o = g & 1;
    float p = 0.0f;
    for (int i = s; i < NATOMS; i += 32) p += outBI[(b * NATOMS + i) * COUT + o];
    red[tid] = p;
    __syncthreads();
    if (tid < 8) {
        float sum = 0.0f;
        for (int q = 0; q < 32; ++q) sum += red[tid * 32 + q];
        red2[tid] = sum;
    }
    __syncthreads();
    if (tid < BATCH) {
        float p0 = red2[tid * 2 + 0] * (1.0f / (float)NATOMS);
        float p1 = red2[tid * 2 + 1] * (1.0f / (float)NATOMS);
        out[tid] = p0 * lw[0] + p1 * lw[1] + lb[0];
    }
}

// ---------------------------------------------------------------------------
extern "C" void kernel_launch(void* const* d_in, const int* in_sizes, int n_in,
                              void* d_out, int out_size, void* d_ws, size_t ws_size,
                              hipStream_t stream) {
    const float* feat = (const float*)d_in[0];   // [4,286,23]
    const float* geo  = (const float*)d_in[1];   // [4,286,3]
    // d_in[2] = num_atoms (static 286, unused)
    const float* w_in = (const float*)d_in[3];   // [3,100]
    const float* w_h  = (const float*)d_in[4];   // [49,100,100]
    const float* w_o  = (const float*)d_in[5];   // [100,46]
    const float* lw   = (const float*)d_in[6];   // [2]
    const float* lb   = (const float*)d_in[7];   // [1]

    char* ws = (char*)d_ws;
    __bf16* wS    = (__bf16*)(ws + OFF_WS);
    __bf16* wOutS = (__bf16*)(ws + OFF_WOUT);
    float*  tab   = (float*)(ws + OFF_TAB);
    float*  outBI = (float*)(ws + OFF_OBI);

    const int prep_threads = NLAYERS * 8 * 4 * 64 + 3 * 4 * 64;   // 101,120
    se3_prep<<<(prep_threads + 255) / 256, 256, 0, stream>>>(w_h, w_o, wS, wOutS);
    se3_table<<<T_TAB / RB, 256, 0, stream>>>(w_in, wS, wOutS, tab);
    se3_conv<<<BATCH * NATOMS, 256, 0, stream>>>(feat, geo, tab, outBI);
    se3_final<<<1, 256, 0, stream>>>(outBI, lw, lb, (float*)d_out);
}